// Round 6
// baseline (560.009 us; speedup 1.0000x reference)
//
#include <hip/hip_runtime.h>
#include <math.h>

#define N_ROWS 16384
#define M_ROWS 16384
#define DIM    512
#define JS     8        // j-splits in pass1
#define KCAND  256      // max rescore candidates
#define DELTA  0.40f    // selection margin (fp8 dist err sigma ~0.03 -> 13 sigma)

typedef __attribute__((ext_vector_type(8))) int   int8v;
typedef __attribute__((ext_vector_type(4))) int   int4v;
typedef __attribute__((ext_vector_type(4))) float floatx4;

// ---------------- 1. convert fp32 -> fp8 e4m3 (HW cvt), exact row norms, init control ----------------
// Note: cvt_pk byte order is irrelevant for correctness: the same k-permutation is
// applied to x and y, so dot products are unchanged; x_sq/y_sq use exact fp32.
__global__ __launch_bounds__(256) void convert_kernel(const float* __restrict__ x, const float* __restrict__ y,
                                                      unsigned char* __restrict__ xh8, unsigned char* __restrict__ yh8,
                                                      float* __restrict__ x_sq, float* __restrict__ y_sq,
                                                      unsigned int* __restrict__ gmax_bits,
                                                      unsigned int* __restrict__ cnt,
                                                      unsigned int* __restrict__ done1,
                                                      unsigned int* __restrict__ done2,
                                                      int* __restrict__ cand) {
    if (blockIdx.x == 0) {
        if (threadIdx.x < KCAND) cand[threadIdx.x] = 0;
        if (threadIdx.x == 0) { *gmax_bits = 0u; *cnt = 0u; *done1 = 0u; *done2 = 0u; }
    }
    int wave = threadIdx.x >> 6, lane = threadIdx.x & 63;
    int row = blockIdx.x * 4 + wave;
    const float* src; unsigned char* dst8; float* dsq; int r;
    if (row < N_ROWS) { r = row;          src = x; dst8 = xh8; dsq = x_sq; }
    else              { r = row - N_ROWS; src = y; dst8 = yh8; dsq = y_sq; }
    const float4* s4 = (const float4*)(src + (size_t)r * DIM);
    float4 a = s4[lane * 2];
    float4 b = s4[lane * 2 + 1];
    float s = a.x*a.x + a.y*a.y + a.z*a.z + a.w*a.w
            + b.x*b.x + b.y*b.y + b.z*b.z + b.w*b.w;
    uint2 pk;
    int w0 = 0, w1 = 0;
    w0 = __builtin_amdgcn_cvt_pk_fp8_f32(a.x, a.y, w0, false);
    w0 = __builtin_amdgcn_cvt_pk_fp8_f32(a.z, a.w, w0, true);
    w1 = __builtin_amdgcn_cvt_pk_fp8_f32(b.x, b.y, w1, false);
    w1 = __builtin_amdgcn_cvt_pk_fp8_f32(b.z, b.w, w1, true);
    pk.x = (unsigned)w0; pk.y = (unsigned)w1;
    *(uint2*)(dst8 + (size_t)r * DIM + lane * 8) = pk;
    #pragma unroll
    for (int off = 32; off > 0; off >>= 1) s += __shfl_down(s, off, 64);
    if (lane == 0) dsq[r] = s;
}

// ---------------- 2. pass1: MX-fp8 MFMA (unit scales), min_j(y_sq[j] - 2 x.y) ----------------
// R3-proven config: 128x128 tile, BK=128 bytes, global_load_lds(16B), XOR-8 swizzle,
// 4 waves (2x2) each 64x64 = 4x4 frags of 16x16x128
__device__ __forceinline__ int8v read_frag(const unsigned char* base, int row, int quad) {
    int s = row & 7;
    int c0 = ((quad << 1) | 0) ^ s;
    int c1 = ((quad << 1) | 1) ^ s;
    int4v lo = *(const int4v*)(base + row * 128 + c0 * 16);
    int4v hi = *(const int4v*)(base + row * 128 + c1 * 16);
    int8v r;
    r[0] = lo[0]; r[1] = lo[1]; r[2] = lo[2]; r[3] = lo[3];
    r[4] = hi[0]; r[5] = hi[1]; r[6] = hi[2]; r[7] = hi[3];
    return r;
}

__global__ __launch_bounds__(256) void pass1_kernel(const unsigned char* __restrict__ xh8,
                                                    const unsigned char* __restrict__ yh8,
                                                    const float* __restrict__ y_sq,
                                                    float* __restrict__ part) {
    __shared__ __align__(16) unsigned char As[128 * 128];
    __shared__ __align__(16) unsigned char Bs[128 * 128];
    __shared__ float red[2][128];

    const int t = threadIdx.x;
    const int wid = t >> 6, lane = t & 63;
    const int wm = wid >> 1, wn = wid & 1;          // wave tile: rows wm*64, cols wn*64
    const int col = lane & 15, quad = lane >> 4;    // MFMA lane coords (16x16 C-layout)
    const int i0 = blockIdx.x * 128;
    const int jsplit = blockIdx.y;

    // staging role: waves 0,1 -> As halves; waves 2,3 -> Bs halves
    const unsigned char* sSrc = (wid < 2) ? xh8 : yh8;
    unsigned char* sDst = (wid < 2) ? As : Bs;
    const int sBase = (wid & 1) * 64;
    const int rr = lane >> 3;                 // row-in-8-group
    const int p  = lane & 7;                  // chunk position this lane fills
    const int srcChunkOff = ((p ^ rr) << 4);  // swizzled global chunk

    float minv[16];
    #pragma unroll
    for (int i = 0; i < 16; ++i) minv[i] = __builtin_inff();

    for (int jt = 0; jt < (M_ROWS / JS) / 128; ++jt) {
        const int j0 = jsplit * (M_ROWS / JS) + jt * 128;
        const int gBase = (wid < 2) ? i0 : j0;
        floatx4 acc[4][4];
        #pragma unroll
        for (int mt = 0; mt < 4; ++mt)
            #pragma unroll
            for (int nt = 0; nt < 4; ++nt) acc[mt][nt] = (floatx4){0.f, 0.f, 0.f, 0.f};

        for (int kc = 0; kc < DIM; kc += 128) {
            #pragma unroll
            for (int r = 0; r < 8; ++r) {
                const unsigned char* gp = sSrc + (size_t)(gBase + sBase + r * 8 + rr) * DIM + kc + srcChunkOff;
                unsigned char* lp = sDst + (sBase + r * 8) * 128;   // wave-uniform; HW adds lane*16B
                __builtin_amdgcn_global_load_lds((const __attribute__((address_space(1))) void*)gp,
                                                 (__attribute__((address_space(3))) void*)lp, 16, 0, 0);
            }
            __syncthreads();
            int8v afr[4], bfr[4];
            #pragma unroll
            for (int mt = 0; mt < 4; ++mt) afr[mt] = read_frag(As, wm * 64 + mt * 16 + col, quad);
            #pragma unroll
            for (int nt = 0; nt < 4; ++nt) bfr[nt] = read_frag(Bs, wn * 64 + nt * 16 + col, quad);
            #pragma unroll
            for (int mt = 0; mt < 4; ++mt)
                #pragma unroll
                for (int nt = 0; nt < 4; ++nt)
                    acc[mt][nt] = __builtin_amdgcn_mfma_scale_f32_16x16x128_f8f6f4(
                        afr[mt], bfr[nt], acc[mt][nt],
                        0, 0,          // cbsz=fp8(e4m3), blgp=fp8(e4m3)
                        0, 127,        // scale_a = E8M0 127 = 1.0
                        0, 127);       // scale_b = 1.0
            __syncthreads();
        }
        // fold y_sq, running min over j (x_sq added later; sqrt monotone)
        #pragma unroll
        for (int nt = 0; nt < 4; ++nt) {
            float q = y_sq[j0 + wn * 64 + nt * 16 + col];
            #pragma unroll
            for (int mt = 0; mt < 4; ++mt)
                #pragma unroll
                for (int r = 0; r < 4; ++r)
                    minv[mt * 4 + r] = fminf(minv[mt * 4 + r], q - 2.f * acc[mt][nt][r]);
        }
    }

    // reduce over the 16 col-lanes (C-layout: col = lane&15, row = quad*4+r)
    #pragma unroll
    for (int i = 0; i < 16; ++i) {
        float v = minv[i];
        v = fminf(v, __shfl_xor(v, 1, 64));
        v = fminf(v, __shfl_xor(v, 2, 64));
        v = fminf(v, __shfl_xor(v, 4, 64));
        v = fminf(v, __shfl_xor(v, 8, 64));
        minv[i] = v;
    }
    if (col == 0) {
        #pragma unroll
        for (int mt = 0; mt < 4; ++mt)
            #pragma unroll
            for (int r = 0; r < 4; ++r)
                red[wn][wm * 64 + mt * 16 + quad * 4 + r] = minv[mt * 4 + r];
    }
    __syncthreads();
    if (t < 128)
        part[(size_t)(i0 + t) * JS + jsplit] = fminf(red[0][t], red[1][t]);
}

// ---------------- 3. fused: per-row approx value, global max, candidate select ----------------
__global__ __launch_bounds__(256) void maxsel_kernel(const float* __restrict__ part,
                                                     const float* __restrict__ x_sq,
                                                     float* __restrict__ aval,
                                                     unsigned int* __restrict__ gmax_bits,
                                                     unsigned int* __restrict__ done1,
                                                     unsigned int* __restrict__ cnt,
                                                     int* __restrict__ cand) {
    __shared__ float sm[256];
    __shared__ int last_flag;
    int t = threadIdx.x;
    int row = blockIdx.x * 256 + t;
    float4 p0 = *(const float4*)(part + (size_t)row * JS);
    float4 p1 = *(const float4*)(part + (size_t)row * JS + 4);
    float m = fminf(fminf(fminf(p0.x, p0.y), fminf(p0.z, p0.w)),
                    fminf(fminf(p1.x, p1.y), fminf(p1.z, p1.w)));
    float v = sqrtf(fmaxf(x_sq[row] + m, 0.f));
    aval[row] = v;
    sm[t] = v;
    __syncthreads();
    for (int s = 128; s > 0; s >>= 1) {
        if (t < s) sm[t] = fmaxf(sm[t], sm[t + s]);
        __syncthreads();
    }
    __threadfence();
    if (t == 0) {
        atomicMax(gmax_bits, __float_as_uint(sm[0]));  // v>=0: uint order == float order
        __threadfence();
        unsigned ticket = atomicAdd(done1, 1u);
        last_flag = (ticket == gridDim.x - 1) ? 1 : 0;
    }
    __syncthreads();
    if (last_flag) {
        __builtin_amdgcn_fence(__ATOMIC_ACQUIRE, "agent");
        float gmax = __uint_as_float(__hip_atomic_load(gmax_bits, __ATOMIC_RELAXED, __HIP_MEMORY_SCOPE_AGENT));
        float thr = gmax - DELTA;
        for (int i = t; i < N_ROWS; i += 256) {
            float av = __hip_atomic_load(&aval[i], __ATOMIC_RELAXED, __HIP_MEMORY_SCOPE_AGENT);
            if (av >= thr) {
                unsigned s = atomicAdd(cnt, 1u);
                if (s < KCAND) cand[s] = i;
            }
        }
    }
}

// ---------------- 4. fused: exact fp32 rescore + final argmax (last-block) ----------------
// 16 cand x 128 centers per block; 256 threads: 2 cand x 4 centers each
#define LDB 132
__global__ __launch_bounds__(256) void rescore_kernel(const float* __restrict__ x, const float* __restrict__ y,
                                                      const float* __restrict__ y_sq,
                                                      const float* __restrict__ x_sq,
                                                      const int* __restrict__ cand,
                                                      const unsigned int* __restrict__ cnt,
                                                      unsigned int* __restrict__ done2,
                                                      float* __restrict__ part2,
                                                      float* __restrict__ out) {
    __shared__ float As[32 * 16];        // [k][cand], stride 16
    __shared__ __align__(16) float Bs[32 * LDB];
    __shared__ float red[16][33];
    __shared__ float sv[256];
    __shared__ int   si[256];
    __shared__ int last_flag;

    int t = threadIdx.x;
    int tx = t & 31, ty = t >> 5;        // tx: 4 centers, ty: 2 cand
    int i0 = blockIdx.x * 16;
    int j0 = blockIdx.y * 128;
    unsigned n = __hip_atomic_load(cnt, __ATOMIC_RELAXED, __HIP_MEMORY_SCOPE_AGENT);
    if (n > KCAND) n = KCAND;
    bool active = (unsigned)i0 < n;

    if (active) {
        float acc[2][4];
        #pragma unroll
        for (int c = 0; c < 2; ++c)
            #pragma unroll
            for (int d = 0; d < 4; ++d) acc[c][d] = 0.f;

        int srow = t >> 3;                   // 0..31
        int skq  = (t & 7) * 4;
        int arow = cand[i0 + (srow & 15)];

        for (int kc = 0; kc < DIM; kc += 32) {
            if (t < 128) {
                float4 v = *(const float4*)(x + (size_t)arow * DIM + kc + skq);
                As[(skq + 0) * 16 + srow] = v.x;
                As[(skq + 1) * 16 + srow] = v.y;
                As[(skq + 2) * 16 + srow] = v.z;
                As[(skq + 3) * 16 + srow] = v.w;
            }
            #pragma unroll
            for (int it = 0; it < 4; ++it) {
                int row = it * 32 + srow;
                float4 v = *(const float4*)(y + (size_t)(j0 + row) * DIM + kc + skq);
                Bs[(skq + 0) * LDB + row] = v.x;
                Bs[(skq + 1) * LDB + row] = v.y;
                Bs[(skq + 2) * LDB + row] = v.z;
                Bs[(skq + 3) * LDB + row] = v.w;
            }
            __syncthreads();
            #pragma unroll 8
            for (int k = 0; k < 32; ++k) {
                float a0 = As[k * 16 + ty * 2];
                float a1 = As[k * 16 + ty * 2 + 1];
                float4 b = *(const float4*)&Bs[k * LDB + tx * 4];
                float bv[4] = {b.x, b.y, b.z, b.w};
                #pragma unroll
                for (int d = 0; d < 4; ++d) {
                    acc[0][d] = fmaf(a0, bv[d], acc[0][d]);
                    acc[1][d] = fmaf(a1, bv[d], acc[1][d]);
                }
            }
            __syncthreads();
        }

        float4 q = *(const float4*)(y_sq + j0 + tx * 4);
        float qv[4] = {q.x, q.y, q.z, q.w};
        float mv[2] = {__builtin_inff(), __builtin_inff()};
        #pragma unroll
        for (int c = 0; c < 2; ++c)
            #pragma unroll
            for (int d = 0; d < 4; ++d)
                mv[c] = fminf(mv[c], qv[d] - 2.f * acc[c][d]);
        #pragma unroll
        for (int c = 0; c < 2; ++c) red[ty * 2 + c][tx] = mv[c];
        __syncthreads();
        if (t < 16) {
            float m = red[t][0];
            #pragma unroll
            for (int xx = 1; xx < 32; ++xx) m = fminf(m, red[t][xx]);
            part2[(size_t)(i0 + t) * 128 + blockIdx.y] = m;
        }
    }

    // ---- last-block final reduction ----
    __threadfence();
    __syncthreads();
    if (t == 0) {
        unsigned ticket = atomicAdd(done2, 1u);
        last_flag = (ticket == gridDim.x * gridDim.y - 1) ? 1 : 0;
    }
    __syncthreads();
    if (!last_flag) return;
    __builtin_amdgcn_fence(__ATOMIC_ACQUIRE, "agent");

    float m = __builtin_inff();
    if (t < (int)n) {
        for (int c = 0; c < 128; ++c)
            m = fminf(m, __hip_atomic_load(&part2[(size_t)t * 128 + c], __ATOMIC_RELAXED, __HIP_MEMORY_SCOPE_AGENT));
    }
    int row = cand[t];
    float v = (t < (int)n) ? sqrtf(fmaxf(x_sq[row] + m, 0.f)) : -__builtin_inff();
    sv[t] = v; si[t] = row;
    __syncthreads();
    for (int s = 128; s > 0; s >>= 1) {
        if (t < s) {
            float v2 = sv[t + s]; int i2 = si[t + s];
            if (v2 > sv[t] || (v2 == sv[t] && i2 < si[t])) { sv[t] = v2; si[t] = i2; }
        }
        __syncthreads();
    }
    if (t == 0) { out[0] = sv[0]; out[1] = (float)si[0]; }
}

extern "C" void kernel_launch(void* const* d_in, const int* in_sizes, int n_in,
                              void* d_out, int out_size, void* d_ws, size_t ws_size,
                              hipStream_t stream) {
    const float* x = (const float*)d_in[0];
    const float* y = (const float*)d_in[1];
    float* out = (float*)d_out;

    char* w = (char*)d_ws;
    unsigned char* xh8 = (unsigned char*)w;                           // 8 MB
    unsigned char* yh8 = (unsigned char*)(w + (size_t)8388608);       // 8 MB
    float* x_sq = (float*)(w + (size_t)16777216);                     // N
    float* y_sq = x_sq + N_ROWS;                                      // M
    float* part = y_sq + M_ROWS;                                      // N*JS
    float* aval = part + (size_t)N_ROWS * JS;                         // N
    float* part2 = aval + N_ROWS;                                     // KCAND*128
    int* cand = (int*)(part2 + (size_t)KCAND * 128);                  // KCAND
    unsigned int* gmax_bits = (unsigned int*)(cand + KCAND);
    unsigned int* cnt   = gmax_bits + 1;
    unsigned int* done1 = gmax_bits + 2;
    unsigned int* done2 = gmax_bits + 3;

    convert_kernel<<<(N_ROWS + M_ROWS) / 4, 256, 0, stream>>>(x, y, xh8, yh8, x_sq, y_sq,
                                                              gmax_bits, cnt, done1, done2, cand);
    dim3 g1(N_ROWS / 128, JS);
    pass1_kernel<<<g1, 256, 0, stream>>>(xh8, yh8, y_sq, part);
    maxsel_kernel<<<N_ROWS / 256, 256, 0, stream>>>(part, x_sq, aval, gmax_bits, done1, cnt, cand);
    dim3 g2(KCAND / 16, M_ROWS / 128);
    rescore_kernel<<<g2, 256, 0, stream>>>(x, y, y_sq, x_sq, cand, cnt, done2, part2, out);
}

// Round 7
// 341.878 us; speedup vs baseline: 1.6380x; 1.6380x over previous
//
#include <hip/hip_runtime.h>
#include <math.h>

#define N_ROWS 16384
#define M_ROWS 16384
#define DIM    512
#define JS     8        // j-splits in pass1
#define KCAND  256      // max rescore candidates
#define DELTA  0.40f    // selection margin (fp8 dist err sigma ~0.034 -> ~12 sigma)

typedef __attribute__((ext_vector_type(8))) int   int8v;
typedef __attribute__((ext_vector_type(4))) int   int4v;
typedef __attribute__((ext_vector_type(4))) float floatx4;

// ---------------- 1. convert fp32 -> fp8 e4m3 (HW cvt), exact row norms, init control ----------------
// cvt_pk byte order is correctness-irrelevant: the same k-permutation applies to x and y,
// so dot products are unchanged; x_sq/y_sq use exact fp32.
__global__ __launch_bounds__(256) void convert_kernel(const float* __restrict__ x, const float* __restrict__ y,
                                                      unsigned char* __restrict__ xh8, unsigned char* __restrict__ yh8,
                                                      float* __restrict__ x_sq, float* __restrict__ y_sq,
                                                      unsigned int* __restrict__ gmax_bits,
                                                      unsigned int* __restrict__ cnt, int* __restrict__ cand) {
    if (blockIdx.x == 0) {
        if (threadIdx.x < KCAND) cand[threadIdx.x] = 0;
        if (threadIdx.x == 0) { *gmax_bits = 0u; *cnt = 0u; }
    }
    int wave = threadIdx.x >> 6, lane = threadIdx.x & 63;
    int row = blockIdx.x * 4 + wave;
    const float* src; unsigned char* dst8; float* dsq; int r;
    if (row < N_ROWS) { r = row;          src = x; dst8 = xh8; dsq = x_sq; }
    else              { r = row - N_ROWS; src = y; dst8 = yh8; dsq = y_sq; }
    const float4* s4 = (const float4*)(src + (size_t)r * DIM);
    float4 a = s4[lane * 2];
    float4 b = s4[lane * 2 + 1];
    float s = a.x*a.x + a.y*a.y + a.z*a.z + a.w*a.w
            + b.x*b.x + b.y*b.y + b.z*b.z + b.w*b.w;
    uint2 pk;
    int w0 = 0, w1 = 0;
    w0 = __builtin_amdgcn_cvt_pk_fp8_f32(a.x, a.y, w0, false);
    w0 = __builtin_amdgcn_cvt_pk_fp8_f32(a.z, a.w, w0, true);
    w1 = __builtin_amdgcn_cvt_pk_fp8_f32(b.x, b.y, w1, false);
    w1 = __builtin_amdgcn_cvt_pk_fp8_f32(b.z, b.w, w1, true);
    pk.x = (unsigned)w0; pk.y = (unsigned)w1;
    *(uint2*)(dst8 + (size_t)r * DIM + lane * 8) = pk;
    #pragma unroll
    for (int off = 32; off > 0; off >>= 1) s += __shfl_down(s, off, 64);
    if (lane == 0) dsq[r] = s;
}

// ---------------- 2. pass1: MX-fp8 MFMA (unit scales), min_j(y_sq[j] - 2 x.y) ----------------
// R3-proven config: 128x128 tile, BK=128 bytes, global_load_lds(16B), XOR-8 swizzle,
// 4 waves (2x2) each 64x64 = 4x4 frags of 16x16x128
__device__ __forceinline__ int8v read_frag(const unsigned char* base, int row, int quad) {
    int s = row & 7;
    int c0 = ((quad << 1) | 0) ^ s;
    int c1 = ((quad << 1) | 1) ^ s;
    int4v lo = *(const int4v*)(base + row * 128 + c0 * 16);
    int4v hi = *(const int4v*)(base + row * 128 + c1 * 16);
    int8v r;
    r[0] = lo[0]; r[1] = lo[1]; r[2] = lo[2]; r[3] = lo[3];
    r[4] = hi[0]; r[5] = hi[1]; r[6] = hi[2]; r[7] = hi[3];
    return r;
}

__global__ __launch_bounds__(256) void pass1_kernel(const unsigned char* __restrict__ xh8,
                                                    const unsigned char* __restrict__ yh8,
                                                    const float* __restrict__ y_sq,
                                                    float* __restrict__ part) {
    __shared__ __align__(16) unsigned char As[128 * 128];
    __shared__ __align__(16) unsigned char Bs[128 * 128];
    __shared__ float red[2][128];

    const int t = threadIdx.x;
    const int wid = t >> 6, lane = t & 63;
    const int wm = wid >> 1, wn = wid & 1;          // wave tile: rows wm*64, cols wn*64
    const int col = lane & 15, quad = lane >> 4;    // MFMA lane coords (16x16 C-layout)
    const int i0 = blockIdx.x * 128;
    const int jsplit = blockIdx.y;

    // staging role: waves 0,1 -> As halves; waves 2,3 -> Bs halves
    const unsigned char* sSrc = (wid < 2) ? xh8 : yh8;
    unsigned char* sDst = (wid < 2) ? As : Bs;
    const int sBase = (wid & 1) * 64;
    const int rr = lane >> 3;                 // row-in-8-group
    const int p  = lane & 7;                  // chunk position this lane fills
    const int srcChunkOff = ((p ^ rr) << 4);  // swizzled global chunk

    float minv[16];
    #pragma unroll
    for (int i = 0; i < 16; ++i) minv[i] = __builtin_inff();

    for (int jt = 0; jt < (M_ROWS / JS) / 128; ++jt) {
        const int j0 = jsplit * (M_ROWS / JS) + jt * 128;
        const int gBase = (wid < 2) ? i0 : j0;
        floatx4 acc[4][4];
        #pragma unroll
        for (int mt = 0; mt < 4; ++mt)
            #pragma unroll
            for (int nt = 0; nt < 4; ++nt) acc[mt][nt] = (floatx4){0.f, 0.f, 0.f, 0.f};

        for (int kc = 0; kc < DIM; kc += 128) {
            #pragma unroll
            for (int r = 0; r < 8; ++r) {
                const unsigned char* gp = sSrc + (size_t)(gBase + sBase + r * 8 + rr) * DIM + kc + srcChunkOff;
                unsigned char* lp = sDst + (sBase + r * 8) * 128;   // wave-uniform; HW adds lane*16B
                __builtin_amdgcn_global_load_lds((const __attribute__((address_space(1))) void*)gp,
                                                 (__attribute__((address_space(3))) void*)lp, 16, 0, 0);
            }
            __syncthreads();
            int8v afr[4], bfr[4];
            #pragma unroll
            for (int mt = 0; mt < 4; ++mt) afr[mt] = read_frag(As, wm * 64 + mt * 16 + col, quad);
            #pragma unroll
            for (int nt = 0; nt < 4; ++nt) bfr[nt] = read_frag(Bs, wn * 64 + nt * 16 + col, quad);
            #pragma unroll
            for (int mt = 0; mt < 4; ++mt)
                #pragma unroll
                for (int nt = 0; nt < 4; ++nt)
                    acc[mt][nt] = __builtin_amdgcn_mfma_scale_f32_16x16x128_f8f6f4(
                        afr[mt], bfr[nt], acc[mt][nt],
                        0, 0,          // cbsz=fp8(e4m3), blgp=fp8(e4m3)
                        0, 127,        // scale_a = E8M0 127 = 1.0
                        0, 127);       // scale_b = 1.0
            __syncthreads();
        }
        // fold y_sq, running min over j (x_sq added later; sqrt monotone)
        #pragma unroll
        for (int nt = 0; nt < 4; ++nt) {
            float q = y_sq[j0 + wn * 64 + nt * 16 + col];
            #pragma unroll
            for (int mt = 0; mt < 4; ++mt)
                #pragma unroll
                for (int r = 0; r < 4; ++r)
                    minv[mt * 4 + r] = fminf(minv[mt * 4 + r], q - 2.f * acc[mt][nt][r]);
        }
    }

    // reduce over the 16 col-lanes (C-layout: col = lane&15, row = quad*4+r)
    #pragma unroll
    for (int i = 0; i < 16; ++i) {
        float v = minv[i];
        v = fminf(v, __shfl_xor(v, 1, 64));
        v = fminf(v, __shfl_xor(v, 2, 64));
        v = fminf(v, __shfl_xor(v, 4, 64));
        v = fminf(v, __shfl_xor(v, 8, 64));
        minv[i] = v;
    }
    if (col == 0) {
        #pragma unroll
        for (int mt = 0; mt < 4; ++mt)
            #pragma unroll
            for (int r = 0; r < 4; ++r)
                red[wn][wm * 64 + mt * 16 + quad * 4 + r] = minv[mt * 4 + r];
    }
    __syncthreads();
    if (t < 128)
        part[(size_t)(i0 + t) * JS + jsplit] = fminf(red[0][t], red[1][t]);
}

// ---------------- 3a. per-row approx value + global max ----------------
__global__ __launch_bounds__(256) void maxred_kernel(const float* __restrict__ part,
                                                     const float* __restrict__ x_sq,
                                                     float* __restrict__ aval,
                                                     unsigned int* __restrict__ gmax_bits) {
    __shared__ float sm[256];
    int t = threadIdx.x;
    int row = blockIdx.x * 256 + t;
    float4 p0 = *(const float4*)(part + (size_t)row * JS);
    float4 p1 = *(const float4*)(part + (size_t)row * JS + 4);
    float m = fminf(fminf(fminf(p0.x, p0.y), fminf(p0.z, p0.w)),
                    fminf(fminf(p1.x, p1.y), fminf(p1.z, p1.w)));
    float v = sqrtf(fmaxf(x_sq[row] + m, 0.f));
    aval[row] = v;
    sm[t] = v;
    __syncthreads();
    for (int s = 128; s > 0; s >>= 1) {
        if (t < s) sm[t] = fmaxf(sm[t], sm[t + s]);
        __syncthreads();
    }
    if (t == 0) atomicMax(gmax_bits, __float_as_uint(sm[0]));  // v>=0: uint order == float order
}

// ---------------- 3b. select candidates within DELTA of max ----------------
__global__ __launch_bounds__(256) void select_kernel(const float* __restrict__ aval,
                                                     const unsigned int* __restrict__ gmax_bits,
                                                     unsigned int* __restrict__ cnt,
                                                     int* __restrict__ cand) {
    int row = blockIdx.x * 256 + threadIdx.x;
    float gmax = __uint_as_float(*gmax_bits);
    if (aval[row] >= gmax - DELTA) {
        unsigned s = atomicAdd(cnt, 1u);
        if (s < KCAND) cand[s] = row;
    }
}

// ---------------- 4. exact fp32 rescore of candidates vs all centers ----------------
// 16 cand x 128 centers per block; 256 threads: 2 cand x 4 centers each
#define LDB 132
__global__ __launch_bounds__(256) void rescore_kernel(const float* __restrict__ x, const float* __restrict__ y,
                                                      const float* __restrict__ y_sq,
                                                      const int* __restrict__ cand,
                                                      const unsigned int* __restrict__ cnt,
                                                      float* __restrict__ part2) {
    __shared__ float As[32 * 16];        // [k][cand], stride 16
    __shared__ __align__(16) float Bs[32 * LDB];
    __shared__ float red[16][33];

    int t = threadIdx.x;
    int tx = t & 31, ty = t >> 5;        // tx: 4 centers, ty: 2 cand
    int i0 = blockIdx.x * 16;
    int j0 = blockIdx.y * 128;

    if ((unsigned)i0 >= *cnt) return;    // uniform early-exit

    float acc[2][4];
    #pragma unroll
    for (int c = 0; c < 2; ++c)
        #pragma unroll
        for (int d = 0; d < 4; ++d) acc[c][d] = 0.f;

    int srow = t >> 3;                   // 0..31
    int skq  = (t & 7) * 4;
    int arow = cand[i0 + (srow & 15)];

    for (int kc = 0; kc < DIM; kc += 32) {
        if (t < 128) {
            float4 v = *(const float4*)(x + (size_t)arow * DIM + kc + skq);
            As[(skq + 0) * 16 + srow] = v.x;
            As[(skq + 1) * 16 + srow] = v.y;
            As[(skq + 2) * 16 + srow] = v.z;
            As[(skq + 3) * 16 + srow] = v.w;
        }
        #pragma unroll
        for (int it = 0; it < 4; ++it) {
            int row = it * 32 + srow;
            float4 v = *(const float4*)(y + (size_t)(j0 + row) * DIM + kc + skq);
            Bs[(skq + 0) * LDB + row] = v.x;
            Bs[(skq + 1) * LDB + row] = v.y;
            Bs[(skq + 2) * LDB + row] = v.z;
            Bs[(skq + 3) * LDB + row] = v.w;
        }
        __syncthreads();
        #pragma unroll 8
        for (int k = 0; k < 32; ++k) {
            float a0 = As[k * 16 + ty * 2];
            float a1 = As[k * 16 + ty * 2 + 1];
            float4 b = *(const float4*)&Bs[k * LDB + tx * 4];
            float bv[4] = {b.x, b.y, b.z, b.w};
            #pragma unroll
            for (int d = 0; d < 4; ++d) {
                acc[0][d] = fmaf(a0, bv[d], acc[0][d]);
                acc[1][d] = fmaf(a1, bv[d], acc[1][d]);
            }
        }
        __syncthreads();
    }

    float4 q = *(const float4*)(y_sq + j0 + tx * 4);
    float qv[4] = {q.x, q.y, q.z, q.w};
    float mv[2] = {__builtin_inff(), __builtin_inff()};
    #pragma unroll
    for (int c = 0; c < 2; ++c)
        #pragma unroll
        for (int d = 0; d < 4; ++d)
            mv[c] = fminf(mv[c], qv[d] - 2.f * acc[c][d]);
    #pragma unroll
    for (int c = 0; c < 2; ++c) red[ty * 2 + c][tx] = mv[c];
    __syncthreads();
    if (t < 16) {
        float m = red[t][0];
        #pragma unroll
        for (int xx = 1; xx < 32; ++xx) m = fminf(m, red[t][xx]);
        part2[(size_t)(i0 + t) * 128 + blockIdx.y] = m;
    }
}

// ---------------- 5. final: exact min per candidate, argmax with index tie-break ----------------
__global__ __launch_bounds__(256) void final2_kernel(const float* __restrict__ part2,
                                                     const float* __restrict__ x_sq,
                                                     const int* __restrict__ cand,
                                                     const unsigned int* __restrict__ cnt,
                                                     float* __restrict__ out) {
    __shared__ float sv[256];
    __shared__ int si[256];
    int t = threadIdx.x;
    unsigned n = *cnt;
    if (n > KCAND) n = KCAND;
    float m = __builtin_inff();
    if (t < (int)n) {
        const float4* p4 = (const float4*)(part2 + (size_t)t * 128);
        for (int c = 0; c < 32; ++c) {
            float4 v = p4[c];
            m = fminf(m, fminf(fminf(v.x, v.y), fminf(v.z, v.w)));
        }
    }
    int row = cand[t];
    float v = (t < (int)n) ? sqrtf(fmaxf(x_sq[row] + m, 0.f)) : -__builtin_inff();
    sv[t] = v; si[t] = row;
    __syncthreads();
    for (int s = 128; s > 0; s >>= 1) {
        if (t < s) {
            float v2 = sv[t + s]; int i2 = si[t + s];
            if (v2 > sv[t] || (v2 == sv[t] && i2 < si[t])) { sv[t] = v2; si[t] = i2; }
        }
        __syncthreads();
    }
    if (t == 0) { out[0] = sv[0]; out[1] = (float)si[0]; }
}

extern "C" void kernel_launch(void* const* d_in, const int* in_sizes, int n_in,
                              void* d_out, int out_size, void* d_ws, size_t ws_size,
                              hipStream_t stream) {
    const float* x = (const float*)d_in[0];
    const float* y = (const float*)d_in[1];
    float* out = (float*)d_out;

    char* w = (char*)d_ws;
    unsigned char* xh8 = (unsigned char*)w;                           // 8 MB
    unsigned char* yh8 = (unsigned char*)(w + (size_t)8388608);       // 8 MB
    float* x_sq = (float*)(w + (size_t)16777216);                     // N
    float* y_sq = x_sq + N_ROWS;                                      // M
    float* part = y_sq + M_ROWS;                                      // N*JS
    float* aval = part + (size_t)N_ROWS * JS;                         // N
    float* part2 = aval + N_ROWS;                                     // KCAND*128
    int* cand = (int*)(part2 + (size_t)KCAND * 128);                  // KCAND
    unsigned int* gmax_bits = (unsigned int*)(cand + KCAND);
    unsigned int* cnt = gmax_bits + 1;

    convert_kernel<<<(N_ROWS + M_ROWS) / 4, 256, 0, stream>>>(x, y, xh8, yh8, x_sq, y_sq,
                                                              gmax_bits, cnt, cand);
    dim3 g1(N_ROWS / 128, JS);
    pass1_kernel<<<g1, 256, 0, stream>>>(xh8, yh8, y_sq, part);
    maxred_kernel<<<N_ROWS / 256, 256, 0, stream>>>(part, x_sq, aval, gmax_bits);
    select_kernel<<<N_ROWS / 256, 256, 0, stream>>>(aval, gmax_bits, cnt, cand);
    dim3 g2(KCAND / 16, M_ROWS / 128);
    rescore_kernel<<<g2, 256, 0, stream>>>(x, y, y_sq, cand, cnt, part2);
    final2_kernel<<<1, 256, 0, stream>>>(part2, x_sq, cand, cnt, out);
}